// Round 14
// baseline (280.911 us; speedup 1.0000x reference)
//
#include <hip/hip_runtime.h>
#include <hip/hip_fp16.h>

// ---------------------------------------------------------------------------
// GCN forward, pull-based + fused. A(HW) = (AH)W:
//   per layer one kernel: gather A·H rows into LDS (branch-free padded CSR,
//   8 independent load chains; fp16 row payloads, fp32 math), then 128x128
//   fp32 matvec with W staged in two 32 KiB halves.
//   Layer 4's matvec commutes past the mean-pool:
//   out = mean(agg4)·(W4·Wlin) + (b4·Wlin + blin); the ENTIRE tail
//   (layer-4 gather + mean-pool + final matvec) is one 1024-thread kernel,
//   block per graph (32 waves/CU residency).
// ---------------------------------------------------------------------------

__global__ void k_count(const int* __restrict__ dstv, int E, int* __restrict__ cnt) {
    int e = blockIdx.x * blockDim.x + threadIdx.x;
    if (e < E) atomicAdd(&cnt[dstv[e]], 1);
}

// scan over PADDED counts ((deg+3)&~3); also emits dinv from raw deg
__global__ void k_scan1(const int* __restrict__ cnt, int N,
                        int* __restrict__ rowptr, int* __restrict__ bsums,
                        float* __restrict__ dinv) {
    __shared__ int sh[256];
    const int t = threadIdx.x;
    const int i = blockIdx.x * 256 + t;
    const int v = (i < N) ? cnt[i] : 0;
    const int pv = (v + 3) & ~3;
    if (i < N) dinv[i] = 1.0f / sqrtf((float)(v + 1));  // +1 self loop
    sh[t] = pv;
    __syncthreads();
    for (int off = 1; off < 256; off <<= 1) {
        int add = (t >= off) ? sh[t - off] : 0;
        __syncthreads();
        sh[t] += add;
        __syncthreads();
    }
    if (i < N) rowptr[i] = sh[t] - pv;
    if (t == 255) bsums[blockIdx.x] = sh[255];
}

__global__ void k_scan2(int* __restrict__ bsums, int nb) {
    __shared__ int sh[256];
    const int t = threadIdx.x;
    const int v = (t < nb) ? bsums[t] : 0;
    sh[t] = v;
    __syncthreads();
    for (int off = 1; off < 256; off <<= 1) {
        int add = (t >= off) ? sh[t - off] : 0;
        __syncthreads();
        sh[t] += add;
        __syncthreads();
    }
    if (t < nb) bsums[t] = sh[t] - v;
}

__global__ void k_scan3(int* __restrict__ rowptr, const int* __restrict__ bsums,
                        int* __restrict__ cnt, int N) {
    const int i = blockIdx.x * blockDim.x + threadIdx.x;
    if (i < N) {
        rowptr[i] += bsums[i >> 8];
        if (i == N - 1) rowptr[N] = rowptr[i] + ((cnt[i] + 3) & ~3);
        cnt[i] = 0;                            // becomes fill cursor
    }
}

// packed edge record: .x = src index (bit pattern), .y = dinv[src]*dinv[dst]
// pad slots (memset to 0) = {src 0, weight 0.0}
__global__ void k_fill(const int* __restrict__ srcv, const int* __restrict__ dstv,
                       const int* __restrict__ rowptr, int* __restrict__ cur,
                       const float* __restrict__ dinv,
                       float2* __restrict__ csr_pack, int E) {
    int e = blockIdx.x * blockDim.x + threadIdx.x;
    if (e < E) {
        const int d = dstv[e];
        const int s = srcv[e];
        const int slot = atomicAdd(&cur[d], 1);
        float2 rec;
        rec.x = __int_as_float(s);
        rec.y = dinv[s] * dinv[d];
        csr_pack[rowptr[d] + slot] = rec;
    }
}

// store float4 as 4 halves (8B)
__device__ __forceinline__ void st_h4(__half* p, float4 v) {
    float2 raw;
    ((__half2*)&raw)[0] = __floats2half2_rn(v.x, v.y);
    ((__half2*)&raw)[1] = __floats2half2_rn(v.z, v.w);
    *(float2*)p = raw;
}

// Fused independent setup work, dispatched by blockIdx range:
//   [0, cvtB)                 : x fp32 -> fp16
//   [cvtB, cvtB+cmbB)         : Wc = W4@Wlin, bc = b4@Wlin + blin
//   [cvtB+cmbB, ...)          : start[g] = lower_bound(batch, g)
__global__ void k_setup(const float* __restrict__ x, __half* __restrict__ x16, int n4,
                        const float* __restrict__ W4, const float* __restrict__ Wlin,
                        const float* __restrict__ b4, const float* __restrict__ blin,
                        float* __restrict__ Wc, float* __restrict__ bc, int T,
                        const int* __restrict__ batch, int N, int G,
                        int* __restrict__ start, int cvtB, int cmbB)
{
    const int b = blockIdx.x;
    const int t = threadIdx.x;
    if (b < cvtB) {
        const int i = b * 256 + t;
        if (i < n4) {
            const float4 v = ((const float4*)x)[i];
            st_h4(x16 + 4 * i, v);
        }
    } else if (b < cvtB + cmbB) {
        const int idx = (b - cvtB) * 256 + t;
        if (idx < 128 * T) {
            const int k = idx / T, tt = idx % T;
            float acc = 0.f;
            #pragma unroll 8
            for (int j = 0; j < 128; ++j)
                acc = fmaf(W4[k * 128 + j], Wlin[j * T + tt], acc);
            Wc[idx] = acc;
        }
        if (idx < T) {
            float acc = blin[idx];
            #pragma unroll 8
            for (int j = 0; j < 128; ++j)
                acc = fmaf(b4[j], Wlin[j * T + idx], acc);
            bc[idx] = acc;
        }
    } else {
        const int g = (b - cvtB - cmbB) * 256 + t;
        if (g > G) return;
        int lo = 0, hi = N;
        while (lo < hi) {
            const int mid = (lo + hi) >> 1;
            if (batch[mid] < g) lo = mid + 1; else hi = mid;
        }
        start[g] = lo;
    }
}

// mixed-precision FMA: acc(f32) += s(f32) * h(fp16x4)
__device__ __forceinline__ void fma4mix(float4& acc, float s, uint2 raw) {
    const __half* h = (const __half*)&raw;
    acc.x = fmaf(s, __half2float(h[0]), acc.x);
    acc.y = fmaf(s, __half2float(h[1]), acc.y);
    acc.z = fmaf(s, __half2float(h[2]), acc.z);
    acc.w = fmaf(s, __half2float(h[3]), acc.w);
}

// Gather aggregated rows n0 AND n1 from fp16 H, interleaved 4-wide each:
// 8 independent {record -> row} load chains. Branch-free body: rows padded
// to x4 records, exhausted rows redirect their CHUNK ADDRESS to the dummy
// zero-chunk.
__device__ __forceinline__ void gather_pair2(
    int n0, int n1, int v0, int v1,
    const __half* __restrict__ Hin,
    const int* __restrict__ rowptr, const float2* __restrict__ pk,
    const float* __restrict__ dinv, int lane, int dummy,
    float4& r0, float4& r1)
{
    const int nc0 = v0 ? n0 : 0;
    const int nc1 = v1 ? n1 : 0;
    const float dn0 = v0 ? dinv[nc0] : 0.f;
    const float dn1 = v1 ? dinv[nc1] : 0.f;
    int c0 = rowptr[nc0];
    int c1 = rowptr[nc1];
    const int e0 = v0 ? rowptr[nc0 + 1] : c0;
    const int e1 = v1 ? rowptr[nc1 + 1] : c1;

    const uint2 s0v = *(const uint2*)(Hin + (size_t)nc0 * 128 + 4 * lane);
    const uint2 s1v = *(const uint2*)(Hin + (size_t)nc1 * 128 + 4 * lane);
    float4 p0 = make_float4(0.f, 0.f, 0.f, 0.f);
    float4 q0 = make_float4(0.f, 0.f, 0.f, 0.f);
    float4 p1 = make_float4(0.f, 0.f, 0.f, 0.f);
    float4 q1 = make_float4(0.f, 0.f, 0.f, 0.f);
    fma4mix(p0, dn0 * dn0, s0v);
    fma4mix(q0, dn1 * dn1, s1v);

    while (c0 < e0 || c1 < e1) {
        const int a0 = (c0 < e0) ? c0 : dummy;   // chunk-level select only
        const int a1 = (c1 < e1) ? c1 : dummy;
        const float2 ra0 = pk[a0];
        const float2 ra1 = pk[a0 + 1];
        const float2 ra2 = pk[a0 + 2];
        const float2 ra3 = pk[a0 + 3];
        const float2 rb0 = pk[a1];
        const float2 rb1 = pk[a1 + 1];
        const float2 rb2 = pk[a1 + 2];
        const float2 rb3 = pk[a1 + 3];
        const uint2 va0 = *(const uint2*)(Hin + (size_t)__float_as_int(ra0.x) * 128 + 4 * lane);
        const uint2 va1 = *(const uint2*)(Hin + (size_t)__float_as_int(ra1.x) * 128 + 4 * lane);
        const uint2 va2 = *(const uint2*)(Hin + (size_t)__float_as_int(ra2.x) * 128 + 4 * lane);
        const uint2 va3 = *(const uint2*)(Hin + (size_t)__float_as_int(ra3.x) * 128 + 4 * lane);
        const uint2 vb0 = *(const uint2*)(Hin + (size_t)__float_as_int(rb0.x) * 128 + 4 * lane);
        const uint2 vb1 = *(const uint2*)(Hin + (size_t)__float_as_int(rb1.x) * 128 + 4 * lane);
        const uint2 vb2 = *(const uint2*)(Hin + (size_t)__float_as_int(rb2.x) * 128 + 4 * lane);
        const uint2 vb3 = *(const uint2*)(Hin + (size_t)__float_as_int(rb3.x) * 128 + 4 * lane);
        fma4mix(p0, ra0.y, va0); fma4mix(p1, ra1.y, va1);
        fma4mix(p0, ra2.y, va2); fma4mix(p1, ra3.y, va3);
        fma4mix(q0, rb0.y, vb0); fma4mix(q1, rb1.y, vb1);
        fma4mix(q0, rb2.y, vb2); fma4mix(q1, rb3.y, vb3);
        c0 += 4; c1 += 4;
    }
    p0.x += p1.x; p0.y += p1.y; p0.z += p1.z; p0.w += p1.w;
    q0.x += q1.x; q0.y += q1.y; q0.z += q1.z; q0.w += q1.w;
    r0 = p0;
    r1 = q0;
}

// Fused layer: Hout[n] = fp16( relu( (A·Hin)[n] @ W + bias ) ).
// One 32-row tile/block. W staged in two 64x128 halves; accumulators live
// across both passes. 48 KiB LDS, launch_bounds(512,6). [frozen: proven]
__global__ __launch_bounds__(512, 6) void k_layer(
    const __half* __restrict__ Hin, const float* __restrict__ W,
    const float* __restrict__ bias,
    const int* __restrict__ rowptr, const float2* __restrict__ csr_pack,
    const float* __restrict__ dinv, int dummy,
    __half* __restrict__ Hout, int N)
{
    __shared__ float Wl[64 * 128];    // 32 KiB: half of W [k][c]
    __shared__ float hl[32 * 128];    // 16 KiB: 32 aggregated rows (fp32)
    const int tid = threadIdx.x;
    for (int i = tid; i < 2048; i += 512)
        ((float4*)Wl)[i] = ((const float4*)W)[i];          // k rows 0..63

    const int lane = tid & 31;
    const int grp  = tid >> 5;        // 0..15
    const int rowBase = blockIdx.x << 5;

    const int n0 = rowBase + grp;
    const int n1 = rowBase + grp + 16;
    const int v0 = n0 < N, v1 = n1 < N;
    float4 g0, g1;
    gather_pair2(n0, n1, v0, v1, Hin, rowptr, csr_pack, dinv, lane, dummy, g0, g1);
    if (v0) *(float4*)(hl + grp * 128 + 4 * lane) = g0;
    if (v1) *(float4*)(hl + (grp + 16) * 128 + 4 * lane) = g1;
    __syncthreads();   // hl + Wl(half 0) ready

    float4 a0 = make_float4(0.f, 0.f, 0.f, 0.f);
    float4 a1 = make_float4(0.f, 0.f, 0.f, 0.f);
    // pass 0: k = 0..63
    #pragma unroll 4
    for (int kq = 0; kq < 16; ++kq) {
        const float4 h0 = *(const float4*)(hl + grp * 128 + 4 * kq);
        const float4 h1 = *(const float4*)(hl + (grp + 16) * 128 + 4 * kq);
        const float4* wp = ((const float4*)Wl) + (4 * kq) * 32 + lane;
        const float4 w0 = wp[0];
        const float4 w1 = wp[32];
        const float4 w2 = wp[64];
        const float4 w3 = wp[96];
        a0.x = fmaf(h0.x, w0.x, a0.x); a0.y = fmaf(h0.x, w0.y, a0.y);
        a0.z = fmaf(h0.x, w0.z, a0.z); a0.w = fmaf(h0.x, w0.w, a0.w);
        a0.x = fmaf(h0.y, w1.x, a0.x); a0.y = fmaf(h0.y, w1.y, a0.y);
        a0.z = fmaf(h0.y, w1.z, a0.z); a0.w = fmaf(h0.y, w1.w, a0.w);
        a0.x = fmaf(h0.z, w2.x, a0.x); a0.y = fmaf(h0.z, w2.y, a0.y);
        a0.z = fmaf(h0.z, w2.z, a0.z); a0.w = fmaf(h0.z, w2.w, a0.w);
        a0.x = fmaf(h0.w, w3.x, a0.x); a0.y = fmaf(h0.w, w3.y, a0.y);
        a0.z = fmaf(h0.w, w3.z, a0.z); a0.w = fmaf(h0.w, w3.w, a0.w);
        a1.x = fmaf(h1.x, w0.x, a1.x); a1.y = fmaf(h1.x, w0.y, a1.y);
        a1.z = fmaf(h1.x, w0.z, a1.z); a1.w = fmaf(h1.x, w0.w, a1.w);
        a1.x = fmaf(h1.y, w1.x, a1.x); a1.y = fmaf(h1.y, w1.y, a1.y);
        a1.z = fmaf(h1.y, w1.z, a1.z); a1.w = fmaf(h1.y, w1.w, a1.w);
        a1.x = fmaf(h1.z, w2.x, a1.x); a1.y = fmaf(h1.z, w2.y, a1.y);
        a1.z = fmaf(h1.z, w2.z, a1.z); a1.w = fmaf(h1.z, w2.w, a1.w);
        a1.x = fmaf(h1.w, w3.x, a1.x); a1.y = fmaf(h1.w, w3.y, a1.y);
        a1.z = fmaf(h1.w, w3.z, a1.z); a1.w = fmaf(h1.w, w3.w, a1.w);
    }
    __syncthreads();   // pass-0 Wl reads done
    for (int i = tid; i < 2048; i += 512)
        ((float4*)Wl)[i] = ((const float4*)(W + 64 * 128))[i];  // k rows 64..127
    __syncthreads();   // Wl(half 1) ready
    // pass 1: k = 64..127
    #pragma unroll 4
    for (int kq = 0; kq < 16; ++kq) {
        const float4 h0 = *(const float4*)(hl + grp * 128 + 64 + 4 * kq);
        const float4 h1 = *(const float4*)(hl + (grp + 16) * 128 + 64 + 4 * kq);
        const float4* wp = ((const float4*)Wl) + (4 * kq) * 32 + lane;
        const float4 w0 = wp[0];
        const float4 w1 = wp[32];
        const float4 w2 = wp[64];
        const float4 w3 = wp[96];
        a0.x = fmaf(h0.x, w0.x, a0.x); a0.y = fmaf(h0.x, w0.y, a0.y);
        a0.z = fmaf(h0.x, w0.z, a0.z); a0.w = fmaf(h0.x, w0.w, a0.w);
        a0.x = fmaf(h0.y, w1.x, a0.x); a0.y = fmaf(h0.y, w1.y, a0.y);
        a0.z = fmaf(h0.y, w1.z, a0.z); a0.w = fmaf(h0.y, w1.w, a0.w);
        a0.x = fmaf(h0.z, w2.x, a0.x); a0.y = fmaf(h0.z, w2.y, a0.y);
        a0.z = fmaf(h0.z, w2.z, a0.z); a0.w = fmaf(h0.z, w2.w, a0.w);
        a0.x = fmaf(h0.w, w3.x, a0.x); a0.y = fmaf(h0.w, w3.y, a0.y);
        a0.z = fmaf(h0.w, w3.z, a0.z); a0.w = fmaf(h0.w, w3.w, a0.w);
        a1.x = fmaf(h1.x, w0.x, a1.x); a1.y = fmaf(h1.x, w0.y, a1.y);
        a1.z = fmaf(h1.x, w0.z, a1.z); a1.w = fmaf(h1.x, w0.w, a1.w);
        a1.x = fmaf(h1.y, w1.x, a1.x); a1.y = fmaf(h1.y, w1.y, a1.y);
        a1.z = fmaf(h1.y, w1.z, a1.z); a1.w = fmaf(h1.y, w1.w, a1.w);
        a1.x = fmaf(h1.z, w2.x, a1.x); a1.y = fmaf(h1.z, w2.y, a1.y);
        a1.z = fmaf(h1.z, w2.z, a1.z); a1.w = fmaf(h1.z, w2.w, a1.w);
        a1.x = fmaf(h1.w, w3.x, a1.x); a1.y = fmaf(h1.w, w3.y, a1.y);
        a1.z = fmaf(h1.w, w3.z, a1.z); a1.w = fmaf(h1.w, w3.w, a1.w);
    }

    const float4 bv = ((const float4*)bias)[lane];
    a0.x += bv.x; a0.y += bv.y; a0.z += bv.z; a0.w += bv.w;
    a1.x += bv.x; a1.y += bv.y; a1.z += bv.z; a1.w += bv.w;
    a0.x = fmaxf(a0.x, 0.f); a0.y = fmaxf(a0.y, 0.f);
    a0.z = fmaxf(a0.z, 0.f); a0.w = fmaxf(a0.w, 0.f);
    a1.x = fmaxf(a1.x, 0.f); a1.y = fmaxf(a1.y, 0.f);
    a1.z = fmaxf(a1.z, 0.f); a1.w = fmaxf(a1.w, 0.f);
    if (v0) st_h4(Hout + (size_t)n0 * 128 + 4 * lane, a0);
    if (v1) st_h4(Hout + (size_t)n1 * 128 + 4 * lane, a1);
}

// Fused tail: 1024-thread block per graph (32 gather groups -> 32 waves/CU
// at 2 blocks/CU). Gathers A·h3 rows straight into registers, block-reduces,
// divides by count, applies the combined 128xT matvec.
__global__ __launch_bounds__(1024) void k_tail(
    const int* __restrict__ rowptr, const float2* __restrict__ csr_pack,
    const float* __restrict__ dinv, const __half* __restrict__ Hin,
    const int* __restrict__ startv,
    const float* __restrict__ Wc, const float* __restrict__ bc,
    float* __restrict__ out, int dummy, int T)
{
    __shared__ float red[32 * 128];   // 16 KiB
    const int g = blockIdx.x;
    const int tid = threadIdx.x;
    const int lane = tid & 31;
    const int grp  = tid >> 5;        // 0..31
    const int s0 = startv[g], s1 = startv[g + 1];

    float4 acc = make_float4(0.f, 0.f, 0.f, 0.f);
    for (int r = s0 + grp; r < s1; r += 64) {   // pair (r, r+32) per iter
        const int n1 = r + 32;
        float4 r0, r1;
        gather_pair2(r, n1, 1, n1 < s1, Hin, rowptr, csr_pack, dinv, lane, dummy, r0, r1);
        acc.x += r0.x + r1.x; acc.y += r0.y + r1.y;
        acc.z += r0.z + r1.z; acc.w += r0.w + r1.w;
    }
    *(float4*)(red + grp * 128 + 4 * lane) = acc;
    __syncthreads();

    // reduce 32 partials per channel; 128 threads, one channel each
    if (tid < 128) {
        float s = 0.f;
        #pragma unroll
        for (int k = 0; k < 32; ++k)
            s += red[k * 128 + tid];
        const float inv = 1.0f / fmaxf((float)(s1 - s0), 1.0f);
        red[tid] = s * inv;           // pooled value, reuse red[0][*]
    }
    __syncthreads();

    if (tid < T) {
        float o = bc[tid];
        #pragma unroll 8
        for (int k = 0; k < 128; ++k)
            o = fmaf(red[k], Wc[k * T + tid], o);
        out[g * T + tid] = o;
    }
}

extern "C" void kernel_launch(void* const* d_in, const int* in_sizes, int n_in,
                              void* d_out, int out_size, void* d_ws, size_t ws_size,
                              hipStream_t stream)
{
    const float* x     = (const float*)d_in[0];
    const int*   ei    = (const int*)d_in[1];
    const int*   batch = (const int*)d_in[2];
    const float* W1    = (const float*)d_in[3];
    const float* b1    = (const float*)d_in[4];
    const float* Ws    = (const float*)d_in[5];
    const float* bs    = (const float*)d_in[6];
    const float* Wlin  = (const float*)d_in[7];
    const float* blin  = (const float*)d_in[8];
    float* out = (float*)d_out;

    const int N = in_sizes[0] / 128;
    const int E = in_sizes[1] / 2;
    const int T = in_sizes[8];           // 10
    const int G = out_size / T;          // 512

    const int packCap = E + 3 * N + 4;   // padded records + dummy chunk
    const int dummy   = E + 3 * N;       // 4 zero records live here

    // workspace layout (float offsets), no aliasing:
    float*  ws = (float*)d_ws;
    int*    cnt      = (int*)ws;                     // [N] histogram -> cursor
    int*    rowptr   = (int*)(ws + 50000);           // [N+1]
    int*    bsums    = (int*)(ws + 100016);          // [256]
    int*    start    = (int*)(ws + 100272);          // [G+1]
    float2* csr_pack = (float2*)(ws + 100800);       // [packCap] -> ends ~1780808
    float*  dinv     = ws + 1780816;                 // [N]
    __half* x16      = (__half*)(ws + 1830816);      // [N*128 halves] = 3.2M floats
    __half* bufA16   = (__half*)(ws + 5030816);      // [N*128 halves]
    __half* bufB16   = (__half*)(ws + 8230816);      // [N*128 halves]
    float*  Wc       = ws + 11430816;                // [128*T]
    float*  bc       = ws + 11430816 + 128 * 10;     // [T]

    const int* srcs = ei;
    const int* dsts = ei + E;
    const float* W4 = Ws + 2 * 16384;
    const float* b4 = bs + 2 * 128;

    hipMemsetAsync(cnt, 0, (size_t)N * sizeof(int), stream);
    hipMemsetAsync(csr_pack, 0, (size_t)packCap * sizeof(float2), stream);

    const int nb = (N + 255) / 256;
    k_count <<<(E + 255) / 256, 256, 0, stream>>>(dsts, E, cnt);
    k_scan1 <<<nb, 256, 0, stream>>>(cnt, N, rowptr, bsums, dinv);
    k_scan2 <<<1, 256, 0, stream>>>(bsums, nb);
    k_scan3 <<<nb, 256, 0, stream>>>(rowptr, bsums, cnt, N);
    k_fill  <<<(E + 255) / 256, 256, 0, stream>>>(srcs, dsts, rowptr, cnt, dinv, csr_pack, E);

    const int cvtB = (N * 32 + 255) / 256;           // x -> x16, float4 granules
    const int cmbB = (128 * T + 255) / 256;
    const int bndB = (G + 256) / 256;
    k_setup<<<cvtB + cmbB + bndB, 256, 0, stream>>>(
        x, x16, N * 32, W4, Wlin, b4, blin, Wc, bc, T,
        batch, N, G, start, cvtB, cmbB);

    const int layerBlocks = (N + 31) / 32;   // 1563, one 32-row tile each

    k_layer<<<layerBlocks, 512, 0, stream>>>(x16,    W1,         b1,       rowptr, csr_pack, dinv, dummy, bufA16, N);
    k_layer<<<layerBlocks, 512, 0, stream>>>(bufA16, Ws,         bs,       rowptr, csr_pack, dinv, dummy, bufB16, N);
    k_layer<<<layerBlocks, 512, 0, stream>>>(bufB16, Ws + 16384, bs + 128, rowptr, csr_pack, dinv, dummy, bufA16, N);

    // fused tail: layer-4 gather + mean-pool + combined final matvec
    k_tail<<<G, 1024, 0, stream>>>(rowptr, csr_pack, dinv, bufA16, start, Wc, bc, out, dummy, T);
}